// Round 1
// 9329.769 us; speedup vs baseline: 1.1433x; 1.1433x over previous
//
#include <hip/hip_runtime.h>
#include <math.h>

#define BB   2
#define TT   4096
#define DD   512
#define HH   8
#define HDD  64
#define KK   256
#define FF   2048
#define VV   32000
#define LL   4
#define EPSF 1.1920928955078125e-07f

// ---------------- embed: x = E[tok] + P ----------------
__global__ void embed_k(const int* __restrict__ tok, const float* __restrict__ E,
                        const float* __restrict__ P, float* __restrict__ X) {
    int idx = blockIdx.x * blockDim.x + threadIdx.x;      // B*T*D
    int d  = idx & (DD - 1);
    int bt = idx / DD;
    int t  = bt & (TT - 1);
    X[idx] = E[(size_t)tok[bt] * DD + d] + P[t * DD + d];
}

// ---------------- rmsnorm: H = x * rsqrt(mean(x^2)+eps) * w ----------------
__global__ void rmsnorm_k(const float* __restrict__ X, const float* __restrict__ w,
                          float* __restrict__ Hout) {
    int row = blockIdx.x;                                  // B*T rows
    const float* x = X + (size_t)row * DD;
    int tid = threadIdx.x;                                 // 256
    float v0 = x[tid], v1 = x[tid + 256];
    float ss = v0 * v0 + v1 * v1;
    for (int off = 32; off; off >>= 1) ss += __shfl_down(ss, off);
    __shared__ float red[4];
    __shared__ float sfac;
    if ((tid & 63) == 0) red[tid >> 6] = ss;
    __syncthreads();
    if (tid == 0) {
        float s = red[0] + red[1] + red[2] + red[3];
        sfac = rsqrtf(s * (1.0f / DD) + EPSF);
    }
    __syncthreads();
    float f = sfac;
    Hout[(size_t)row * DD + tid]       = v0 * f * w[tid];
    Hout[(size_t)row * DD + tid + 256] = v1 * f * w[tid + 256];
}

// ---------------- router scores r[b,h,t] = dot(H[b,t,:], Wr[h,:]) ----------------
__global__ void router_k(const float* __restrict__ Hb, const float* __restrict__ Wr,
                         float* __restrict__ R) {
    int t = blockIdx.x, h = blockIdx.y, b = blockIdx.z;
    int lane = threadIdx.x;                                // 64
    const float* x = Hb + ((size_t)(b * TT + t)) * DD;
    const float* w = Wr + h * DD;
    float s = 0.f;
    for (int c = lane; c < DD; c += 64) s += x[c] * w[c];
    for (int off = 32; off; off >>= 1) s += __shfl_down(s, off);
    if (lane == 0) R[((size_t)(b * HH + h)) * TT + t] = s;
}

// ---------------- top-K via rank counting (matches jax.lax.top_k order+ties) ----------------
__global__ void select_k(const float* __restrict__ R, int* __restrict__ IDX) {
    int h = blockIdx.y, b = blockIdx.z;
    const float* r = R + ((size_t)(b * HH + h)) * TT;
    __shared__ float sr[TT];                               // 16 KB
    for (int i = threadIdx.x; i < TT; i += 256) sr[i] = r[i];
    __syncthreads();
    int t = blockIdx.x * 256 + threadIdx.x;
    float v = sr[t];
    int rank = 0;
    for (int u = 0; u < TT; u++) {
        float ru = sr[u];
        rank += (ru > v) || (ru == v && u < t);
    }
    if (rank < KK) IDX[(b * HH + h) * KK + rank] = t;
}

// ---------------- gather + QKV projection for selected tokens only ----------------
__global__ void qkv_k(const float* __restrict__ Hb, const int* __restrict__ IDX,
                      const float* __restrict__ Wq, const float* __restrict__ Wk,
                      const float* __restrict__ Wv,
                      float* __restrict__ QG, float* __restrict__ KG, float* __restrict__ VG) {
    int i = blockIdx.x, h = blockIdx.y, b = blockIdx.z;
    int bh = b * HH + h;
    int ti = IDX[bh * KK + i];
    __shared__ float xr[DD];
    int tid = threadIdx.x;                                 // 192
    for (int c = tid; c < DD; c += 192) xr[c] = Hb[((size_t)(b * TT + ti)) * DD + c];
    __syncthreads();
    int which = tid / 64, d = tid & 63;
    const float* W = (which == 0) ? Wq : (which == 1) ? Wk : Wv;
    const float* wrow = W + (size_t)(h * HDD + d) * DD;
    float s = 0.f;
    for (int c = 0; c < DD; c++) s += xr[c] * wrow[c];
    float* Out = (which == 0) ? QG : (which == 1) ? KG : VG;
    Out[((size_t)(bh * KK + i)) * HDD + d] = s;
}

// ---------------- attention over the gathered 256x256 block ----------------
__global__ void attn_k(const float* __restrict__ QG, const float* __restrict__ KG,
                       const float* __restrict__ VG, const int* __restrict__ IDX,
                       float* __restrict__ OG) {
    int i = blockIdx.x, h = blockIdx.y, b = blockIdx.z;
    int bh = b * HH + h;
    const int* idx = IDX + bh * KK;
    __shared__ float q[HDD];
    __shared__ float a[KK];
    __shared__ float red[4];
    int tid = threadIdx.x;                                 // 256
    int ti = idx[i];
    if (tid < HDD) q[tid] = QG[((size_t)(bh * KK + i)) * HDD + tid];
    __syncthreads();
    int j = tid;
    const float* krow = KG + ((size_t)(bh * KK + j)) * HDD;
    float s = 0.f;
    for (int c = 0; c < HDD; c++) s += q[c] * krow[c];
    int tj = idx[j];
    s = (ti >= tj) ? s * 0.125f : -INFINITY;
    // block max
    float m = s;
    for (int off = 32; off; off >>= 1) m = fmaxf(m, __shfl_down(m, off));
    if ((tid & 63) == 0) red[tid >> 6] = m;
    __syncthreads();
    if (tid == 0) red[0] = fmaxf(fmaxf(red[0], red[1]), fmaxf(red[2], red[3]));
    __syncthreads();
    float mall = red[0];
    float e = expf(s - mall);
    // block sum
    float sum = e;
    for (int off = 32; off; off >>= 1) sum += __shfl_down(sum, off);
    __syncthreads();
    if ((tid & 63) == 0) red[tid >> 6] = sum;
    __syncthreads();
    if (tid == 0) red[0] = red[0] + red[1] + red[2] + red[3];
    __syncthreads();
    float denom = red[0];
    a[tid] = e / denom;
    __syncthreads();
    if (tid < HDD) {
        float o = 0.f;
        for (int jj = 0; jj < KK; jj++) o += a[jj] * VG[((size_t)(bh * KK + jj)) * HDD + tid];
        OG[((size_t)(bh * KK + i)) * HDD + tid] = o;
    }
}

// ---------------- output projection + scatter-add into residual X ----------------
__global__ void oproj_k(const float* __restrict__ OG, const int* __restrict__ IDX,
                        const float* __restrict__ Wo, float* __restrict__ X) {
    int i = blockIdx.x, h = blockIdx.y, b = blockIdx.z;
    int bh = b * HH + h;
    __shared__ float og[HDD];
    int tid = threadIdx.x;                                 // 512
    if (tid < HDD) og[tid] = OG[((size_t)(bh * KK + i)) * HDD + tid];
    __syncthreads();
    int ti = IDX[bh * KK + i];
    const float* wr = Wo + (size_t)tid * DD + h * HDD;     // Wo[dout][h*64 + c]
    float s = 0.f;
    for (int c = 0; c < HDD; c++) s += og[c] * wr[c];
    atomicAdd(&X[((size_t)(b * TT + ti)) * DD + tid], s);
}

// ---------------- tiled f32 GEMM: C = act(A @ B^T + bias), optional +=
// A[M,K] row-major, B[N,K] row-major. 128xTN tile (TN=128 or 64), 256 threads,
// 8x8 (or 8x4) micro-tile in 2x2(1) blocks of 4x4 so all LDS reads are
// ds_read_b128 with <=2-way bank aliasing (free on gfx950).
// K-major LDS, pad to 132/68 floats (16B-aligned rows). Double-buffered,
// register-staged, ONE barrier per K-step (global latency hides under compute).
// Requires: M%128==0, N%TN==0, K%16==0 (all true for this model).
template <int ACT, int ACC, int TN>
__global__ __launch_bounds__(256) void gemm_bt_k(const float* __restrict__ A,
                                                 const float* __restrict__ B,
                                                 const float* __restrict__ bias,
                                                 float* __restrict__ C,
                                                 int M, int N, int Kd) {
    constexpr int NB = TN / 64;
    constexpr int BPAD = (TN == 128) ? 132 : 68;
    __shared__ __attribute__((aligned(16))) float As[2][16][132];
    __shared__ __attribute__((aligned(16))) float Bs[2][16][BPAD];
    const int tid = threadIdx.x;
    const int tx = tid & 15, ty = tid >> 4;
    const int n0 = blockIdx.x * TN;
    const int m0 = blockIdx.y * 128;
    const int lr = tid >> 2;            // 0..63 (row within pass)
    const int lc = (tid & 3) * 4;       // 0,4,8,12 (k offset)
    const float* Ap = A + (size_t)(m0 + lr) * Kd + lc;
    const float* Bp = B + (size_t)(n0 + lr) * Kd + lc;
    const size_t str64 = (size_t)64 * Kd;

    float4 ra[2], rb[NB];
    // prologue: load k-tile 0
    ra[0] = *(const float4*)Ap;
    ra[1] = *(const float4*)(Ap + str64);
    rb[0] = *(const float4*)Bp;
    if constexpr (NB == 2) rb[1] = *(const float4*)(Bp + str64);
#pragma unroll
    for (int j = 0; j < 4; j++) {
        As[0][lc + j][lr]      = ((const float*)&ra[0])[j];
        As[0][lc + j][lr + 64] = ((const float*)&ra[1])[j];
        Bs[0][lc + j][lr]      = ((const float*)&rb[0])[j];
        if constexpr (NB == 2) Bs[0][lc + j][lr + 64] = ((const float*)&rb[1])[j];
    }

    float acc[2][NB][4][4] = {};
    const int nsteps = Kd >> 4;
    int cur = 0;
    for (int t = 0; t < nsteps; t++) {
        if (t + 1 < nsteps) {
            const float* Ap2 = Ap + (t + 1) * 16;
            const float* Bp2 = Bp + (t + 1) * 16;
            ra[0] = *(const float4*)Ap2;
            ra[1] = *(const float4*)(Ap2 + str64);
            rb[0] = *(const float4*)Bp2;
            if constexpr (NB == 2) rb[1] = *(const float4*)(Bp2 + str64);
        }
        __syncthreads();                 // buf[cur] fully written; prev compute done
#pragma unroll
        for (int kk = 0; kk < 16; kk++) {
            float4 av0 = *(const float4*)&As[cur][kk][ty * 4];
            float4 av1 = *(const float4*)&As[cur][kk][64 + ty * 4];
            float4 bv[NB];
            bv[0] = *(const float4*)&Bs[cur][kk][tx * 4];
            if constexpr (NB == 2) bv[1] = *(const float4*)&Bs[cur][kk][64 + tx * 4];
            const float* af0 = (const float*)&av0;
            const float* af1 = (const float*)&av1;
#pragma unroll
            for (int i = 0; i < 4; i++) {
                float a0 = af0[i], a1 = af1[i];
#pragma unroll
                for (int hn = 0; hn < NB; hn++) {
                    const float* bf = (const float*)&bv[hn];
#pragma unroll
                    for (int j = 0; j < 4; j++) {
                        acc[0][hn][i][j] += a0 * bf[j];
                        acc[1][hn][i][j] += a1 * bf[j];
                    }
                }
            }
        }
        if (t + 1 < nsteps) {
            int nxt = cur ^ 1;
#pragma unroll
            for (int j = 0; j < 4; j++) {
                As[nxt][lc + j][lr]      = ((const float*)&ra[0])[j];
                As[nxt][lc + j][lr + 64] = ((const float*)&ra[1])[j];
                Bs[nxt][lc + j][lr]      = ((const float*)&rb[0])[j];
                if constexpr (NB == 2) Bs[nxt][lc + j][lr + 64] = ((const float*)&rb[1])[j];
            }
            cur = nxt;
        }
    }
    // epilogue: bias + act + (optional +=) with float4 stores
#pragma unroll
    for (int hm = 0; hm < 2; hm++) {
#pragma unroll
        for (int i = 0; i < 4; i++) {
            int m = m0 + hm * 64 + ty * 4 + i;
#pragma unroll
            for (int hn = 0; hn < NB; hn++) {
                int n = n0 + hn * 64 + tx * 4;
                float4 v;
                float* vf = (float*)&v;
#pragma unroll
                for (int j = 0; j < 4; j++) {
                    float x = acc[hm][hn][i][j];
                    if (bias) x += bias[n + j];
                    if (ACT == 1) x = x / (1.0f + expf(-x));   // silu
                    vf[j] = x;
                }
                float* Cp = C + (size_t)m * N + n;
                if constexpr (ACC) {
                    float4 old = *(const float4*)Cp;
                    v.x += old.x; v.y += old.y; v.z += old.z; v.w += old.w;
                }
                *(float4*)Cp = v;
            }
        }
    }
}

extern "C" void kernel_launch(void* const* d_in, const int* in_sizes, int n_in,
                              void* d_out, int out_size, void* d_ws, size_t ws_size,
                              hipStream_t stream) {
    const int*   tok = (const int*)d_in[0];
    const float* E   = (const float*)d_in[1];
    const float* P   = (const float*)d_in[2];
    const float* Wr  = (const float*)d_in[3];
    const float* Wq  = (const float*)d_in[4];
    const float* Wk  = (const float*)d_in[5];
    const float* Wv  = (const float*)d_in[6];
    const float* Wo  = (const float*)d_in[7];
    const float* n1  = (const float*)d_in[8];
    const float* n2  = (const float*)d_in[9];
    const float* W1  = (const float*)d_in[10];
    const float* b1  = (const float*)d_in[11];
    const float* W2  = (const float*)d_in[12];
    const float* b2  = (const float*)d_in[13];
    float* OUT = (float*)d_out;

    // X (residual, must survive until lm_head) lives in d_ws: 16 MB.
    float* X = (float*)d_ws;
    // Everything else is dead before the final lm_head fully overwrites d_out,
    // so stage it in the front of d_out (1 GB):
    float* U   = OUT;                  // [8192, 2048] FFN intermediate (64 MB)
    float* Hb  = U + (size_t)8192 * FF;      // [8192, 512] normed activations
    float* R   = Hb + (size_t)8192 * DD;     // [2, 8, 4096] router scores
    float* QG  = R + BB * HH * TT;           // [2,8,256,64] each
    float* KG  = QG + BB * HH * KK * HDD;
    float* VG  = KG + BB * HH * KK * HDD;
    float* OG  = VG + BB * HH * KK * HDD;
    int*   IDX = (int*)(OG + BB * HH * KK * HDD);  // [2,8,256]

    embed_k<<<BB * TT * DD / 256, 256, 0, stream>>>(tok, E, P, X);

    for (int l = 0; l < LL; l++) {
        const float* Wql = Wq + (size_t)l * DD * DD;
        const float* Wkl = Wk + (size_t)l * DD * DD;
        const float* Wvl = Wv + (size_t)l * DD * DD;
        const float* Wol = Wo + (size_t)l * DD * DD;

        rmsnorm_k<<<BB * TT, 256, 0, stream>>>(X, n1 + l * DD, Hb);
        router_k<<<dim3(TT, HH, BB), 64, 0, stream>>>(Hb, Wr + l * HH * DD, R);
        select_k<<<dim3(TT / 256, HH, BB), 256, 0, stream>>>(R, IDX);
        qkv_k<<<dim3(KK, HH, BB), 192, 0, stream>>>(Hb, IDX, Wql, Wkl, Wvl, QG, KG, VG);
        attn_k<<<dim3(KK, HH, BB), 256, 0, stream>>>(QG, KG, VG, IDX, OG);
        oproj_k<<<dim3(KK, HH, BB), 512, 0, stream>>>(OG, IDX, Wol, X);

        rmsnorm_k<<<BB * TT, 256, 0, stream>>>(X, n2 + l * DD, Hb);
        gemm_bt_k<1, 0, 128><<<dim3(FF / 128, BB * TT / 128), 256, 0, stream>>>(
            Hb, W1 + (size_t)l * FF * DD, b1 + l * FF, U, BB * TT, FF, DD);
        gemm_bt_k<0, 1, 64><<<dim3(DD / 64, BB * TT / 128), 256, 0, stream>>>(
            U, W2 + (size_t)l * DD * FF, b2 + l * DD, X, BB * TT, DD, FF);
    }

    // lm_head: OUT = X @ E^T   [8192, 32000]
    gemm_bt_k<0, 0, 128><<<dim3(VV / 128, BB * TT / 128), 256, 0, stream>>>(
        X, E, nullptr, OUT, BB * TT, VV, DD);
}